// Round 1
// baseline (467.550 us; speedup 1.0000x reference)
//
#include <hip/hip_runtime.h>

typedef float f32x4 __attribute__((ext_vector_type(4)));
typedef short s16x8 __attribute__((ext_vector_type(8)));

__device__ __forceinline__ unsigned short f2bf(float f) {
  unsigned int u = __float_as_uint(f);
  u += 0x7fffu + ((u >> 16) & 1u);
  return (unsigned short)(u >> 16);
}

// ---------------- GroupNorm stats: one block per (b,g) ----------------
__global__ __launch_bounds__(256) void gn_stats_k(const float* __restrict__ x,
                                                  float* __restrict__ meanv,
                                                  float* __restrict__ rstdv) {
  const int bg = blockIdx.x;  // b*32+g ; group covers 8 contiguous channels
  const float4* base = (const float4*)(x + (size_t)bg * 8 * 4096);
  float s = 0.f, q = 0.f;
  for (int i = threadIdx.x; i < 8192; i += 256) {
    float4 v = base[i];
    s += v.x + v.y + v.z + v.w;
    q += v.x * v.x + v.y * v.y + v.z * v.z + v.w * v.w;
  }
  for (int o = 32; o; o >>= 1) { s += __shfl_down(s, o); q += __shfl_down(q, o); }
  __shared__ float ss[4], sq[4];
  const int wv = threadIdx.x >> 6;
  if ((threadIdx.x & 63) == 0) { ss[wv] = s; sq[wv] = q; }
  __syncthreads();
  if (threadIdx.x == 0) {
    s = ss[0] + ss[1] + ss[2] + ss[3];
    q = sq[0] + sq[1] + sq[2] + sq[3];
    float mu = s * (1.f / 32768.f);
    float var = q * (1.f / 32768.f) - mu * mu;
    meanv[bg] = mu;
    rstdv[bg] = rsqrtf(var + 1e-6f);
  }
}

// ------------- GroupNorm apply + transpose: write hT[b][t][c] bf16 -------------
__global__ __launch_bounds__(256) void gn_apply_t_k(const float* __restrict__ x,
    const float* __restrict__ gamma, const float* __restrict__ beta,
    const float* __restrict__ meanv, const float* __restrict__ rstdv,
    unsigned short* __restrict__ hT) {
  __shared__ unsigned short tile[64][72];
  const int b = blockIdx.z, c0 = blockIdx.y * 64, t0 = blockIdx.x * 64;
  const int tid = threadIdx.x;
  {
    const int tr = tid >> 4, tc = (tid & 15) * 4;
    const float* xb = x + ((size_t)b * 256 + c0) * 4096 + t0;
    for (int p2 = 0; p2 < 4; ++p2) {
      int cl = p2 * 16 + tr;
      int c = c0 + cl;
      int bg = b * 32 + (c >> 3);
      float ga = gamma[c] * rstdv[bg];
      float be = beta[c] - meanv[bg] * ga;
      float4 v = *(const float4*)(xb + (size_t)cl * 4096 + tc);
      tile[cl][tc + 0] = f2bf(v.x * ga + be);
      tile[cl][tc + 1] = f2bf(v.y * ga + be);
      tile[cl][tc + 2] = f2bf(v.z * ga + be);
      tile[cl][tc + 3] = f2bf(v.w * ga + be);
    }
  }
  __syncthreads();
  {
    const int orow = tid >> 3, oc = (tid & 7) * 8;
    unsigned short* hb = hT + ((size_t)b * 4096 + t0) * 256 + c0;
    for (int p2 = 0; p2 < 2; ++p2) {
      int tl = p2 * 32 + orow;
      s16x8 w;
#pragma unroll
      for (int j = 0; j < 8; ++j) w[j] = (short)tile[oc + j][tl];
      *(s16x8*)(hb + (size_t)tl * 256 + oc) = w;
    }
  }
}

// ---------------- generic 64x64-tile MFMA GEMM ----------------
// OUT[m][n] = sum_k A[m][k] * BT[n][k]   (both operands K-major)
enum { EPI_WT = 0, EPI_PB = 1, EPI_PF = 2, EPI_FIN = 3 };

template <bool AF32, int EPI>
__global__ __launch_bounds__(256) void gemm64_k(
    const void* __restrict__ Ap, long long sA, int lda,
    const unsigned short* __restrict__ Bp, long long sB, int ldb,
    void* __restrict__ Op, long long sO, int ldo,
    const float* __restrict__ bias,
    const float* __restrict__ xadd, long long sX,
    float scale, int K) {
  __shared__ s16x8 lsA[4][64];
  __shared__ s16x8 lsB[4][64];
  const int tid = threadIdx.x;
  const int m0 = blockIdx.y * 64, n0 = blockIdx.x * 64;
  const int z = blockIdx.z;
  const int lane = tid & 63, wv = tid >> 6;
  const int lrow = lane & 15, lg = lane >> 4;
  const int srow = tid >> 2, scg = tid & 3;
  const int swrow = srow ^ (scg << 1);  // bank swizzle

  f32x4 acc[4];
#pragma unroll
  for (int i = 0; i < 4; ++i) acc[i] = (f32x4){0.f, 0.f, 0.f, 0.f};

  const unsigned short* Bb = Bp + (size_t)z * sB + (size_t)(n0 + srow) * ldb + scg * 8;

  for (int k0 = 0; k0 < K; k0 += 32) {
    if (AF32) {
      const float* ap = (const float*)Ap + (size_t)z * sA + (size_t)(m0 + srow) * lda + k0 + scg * 8;
      float4 v0 = *(const float4*)ap;
      float4 v1 = *(const float4*)(ap + 4);
      s16x8 w;
      w[0] = (short)f2bf(v0.x); w[1] = (short)f2bf(v0.y);
      w[2] = (short)f2bf(v0.z); w[3] = (short)f2bf(v0.w);
      w[4] = (short)f2bf(v1.x); w[5] = (short)f2bf(v1.y);
      w[6] = (short)f2bf(v1.z); w[7] = (short)f2bf(v1.w);
      lsA[scg][swrow] = w;
    } else {
      const unsigned short* ap = (const unsigned short*)Ap + (size_t)z * sA + (size_t)(m0 + srow) * lda + k0 + scg * 8;
      lsA[scg][swrow] = *(const s16x8*)ap;
    }
    lsB[scg][swrow] = *(const s16x8*)(Bb + k0);
    __syncthreads();
    s16x8 af = lsA[lg][(wv * 16 + lrow) ^ (lg << 1)];
#pragma unroll
    for (int nt = 0; nt < 4; ++nt) {
      s16x8 bf = lsB[lg][(nt * 16 + lrow) ^ (lg << 1)];
      acc[nt] = __builtin_amdgcn_mfma_f32_16x16x32_bf16(af, bf, acc[nt], 0, 0, 0);
    }
    __syncthreads();
  }

  const int mb = m0 + wv * 16 + lg * 4;
  float bv0 = 0.f, bv1 = 0.f, bv2 = 0.f, bv3 = 0.f;
  if (EPI != EPI_PF) {
    if (bias) { bv0 = bias[mb]; bv1 = bias[mb + 1]; bv2 = bias[mb + 2]; bv3 = bias[mb + 3]; }
  }
#pragma unroll
  for (int nt = 0; nt < 4; ++nt) {
    const int n = n0 + nt * 16 + lrow;
    if (EPI == EPI_WT) {
      ushort4 pk;
      pk.x = f2bf((acc[nt][0] + bv0) * scale);
      pk.y = f2bf((acc[nt][1] + bv1) * scale);
      pk.z = f2bf((acc[nt][2] + bv2) * scale);
      pk.w = f2bf((acc[nt][3] + bv3) * scale);
      *(ushort4*)((unsigned short*)Op + (size_t)z * sO + (size_t)n * ldo + mb) = pk;
    } else if (EPI == EPI_PB) {
      unsigned short* o = (unsigned short*)Op + (size_t)z * sO;
      o[(size_t)(mb + 0) * ldo + n] = f2bf(acc[nt][0] + bv0);
      o[(size_t)(mb + 1) * ldo + n] = f2bf(acc[nt][1] + bv1);
      o[(size_t)(mb + 2) * ldo + n] = f2bf(acc[nt][2] + bv2);
      o[(size_t)(mb + 3) * ldo + n] = f2bf(acc[nt][3] + bv3);
    } else if (EPI == EPI_PF) {
      float* o = (float*)Op + (size_t)z * sO;
      o[(size_t)(mb + 0) * ldo + n] = acc[nt][0];
      o[(size_t)(mb + 1) * ldo + n] = acc[nt][1];
      o[(size_t)(mb + 2) * ldo + n] = acc[nt][2];
      o[(size_t)(mb + 3) * ldo + n] = acc[nt][3];
    } else {
      float* o = (float*)Op + (size_t)z * sO;
      const float* xa = xadd + (size_t)z * sX;
      o[(size_t)(mb + 0) * ldo + n] = acc[nt][0] + bv0 + xa[(size_t)(mb + 0) * ldo + n];
      o[(size_t)(mb + 1) * ldo + n] = acc[nt][1] + bv1 + xa[(size_t)(mb + 1) * ldo + n];
      o[(size_t)(mb + 2) * ldo + n] = acc[nt][2] + bv2 + xa[(size_t)(mb + 2) * ldo + n];
      o[(size_t)(mb + 3) * ldo + n] = acc[nt][3] + bv3 + xa[(size_t)(mb + 3) * ldo + n];
    }
  }
}

// ---------------- per-row softmax stats over S strip ----------------
__global__ __launch_bounds__(256) void row_stats_k(const float* __restrict__ S,
                                                   float* __restrict__ m_out,
                                                   float* __restrict__ r_out) {
  const int q = blockIdx.x;
  const float4* rp = (const float4*)(S + (size_t)q * 4096);
  const int tid = threadIdx.x;
  float4 v[4];
  float mx = -1e30f;
#pragma unroll
  for (int i = 0; i < 4; ++i) {
    v[i] = rp[tid + 256 * i];
    mx = fmaxf(mx, fmaxf(fmaxf(v[i].x, v[i].y), fmaxf(v[i].z, v[i].w)));
  }
  for (int o = 32; o; o >>= 1) mx = fmaxf(mx, __shfl_down(mx, o));
  __shared__ float sm[4], sl[4];
  __shared__ float bm;
  const int wv = tid >> 6;
  if ((tid & 63) == 0) sm[wv] = mx;
  __syncthreads();
  if (tid == 0) bm = fmaxf(fmaxf(sm[0], sm[1]), fmaxf(sm[2], sm[3]));
  __syncthreads();
  mx = bm;
  float s = 0.f;
#pragma unroll
  for (int i = 0; i < 4; ++i) {
    s += __expf(v[i].x - mx) + __expf(v[i].y - mx) + __expf(v[i].z - mx) + __expf(v[i].w - mx);
  }
  for (int o = 32; o; o >>= 1) s += __shfl_down(s, o);
  if ((tid & 63) == 0) sl[wv] = s;
  __syncthreads();
  if (tid == 0) {
    float l = sl[0] + sl[1] + sl[2] + sl[3];
    m_out[q] = mx;
    r_out[q] = 1.f / l;
  }
}

// ------- PT[k][qbase+q] = bf16( exp(S[q][k]-m[q]) * rinv[q] ), tiled transpose -------
__global__ __launch_bounds__(256) void make_pt_k(const float* __restrict__ S,
    const float* __restrict__ mrow, const float* __restrict__ rinv,
    unsigned short* __restrict__ PT, int qbase) {
  __shared__ unsigned short tile[64][72];
  const int k0 = blockIdx.x * 64, ql0 = blockIdx.y * 64;
  const int tid = threadIdx.x;
  {
    const int qr = tid >> 4, kc = (tid & 15) * 4;
    for (int p2 = 0; p2 < 4; ++p2) {
      int qll = p2 * 16 + qr;
      int ql = ql0 + qll;
      float m = mrow[ql], ri = rinv[ql];
      float4 v = *(const float4*)(S + (size_t)ql * 4096 + k0 + kc);
      tile[qll][kc + 0] = f2bf(__expf(v.x - m) * ri);
      tile[qll][kc + 1] = f2bf(__expf(v.y - m) * ri);
      tile[qll][kc + 2] = f2bf(__expf(v.z - m) * ri);
      tile[qll][kc + 3] = f2bf(__expf(v.w - m) * ri);
    }
  }
  __syncthreads();
  {
    const int kr = tid >> 3, qc = (tid & 7) * 8;
    for (int p2 = 0; p2 < 2; ++p2) {
      int kl = p2 * 32 + kr;
      s16x8 w;
#pragma unroll
      for (int j = 0; j < 8; ++j) w[j] = (short)tile[qc + j][kl];
      *(s16x8*)(PT + (size_t)(k0 + kl) * 4096 + qbase + ql0 + qc) = w;
    }
  }
}

extern "C" void kernel_launch(void* const* d_in, const int* in_sizes, int n_in,
                              void* d_out, int out_size, void* d_ws, size_t ws_size,
                              hipStream_t stream) {
  const float* x   = (const float*)d_in[0];
  const float* gns = (const float*)d_in[1];
  const float* gnb = (const float*)d_in[2];
  const float* wq  = (const float*)d_in[3];
  const float* bq  = (const float*)d_in[4];
  const float* wk  = (const float*)d_in[5];
  const float* bk  = (const float*)d_in[6];
  const float* wvp = (const float*)d_in[7];
  const float* bv  = (const float*)d_in[8];
  const float* wo  = (const float*)d_in[9];
  const float* bo  = (const float*)d_in[10];
  float* out = (float*)d_out;

  const int B = 4, C = 256, T = 4096;
  const long long TCe = (long long)T * C;  // 1M elems

  char* p = (char*)d_ws;
  unsigned short* hT = (unsigned short*)p; p += (size_t)B * TCe * 2;
  unsigned short* qT = (unsigned short*)p; p += (size_t)B * TCe * 2;
  unsigned short* kT = (unsigned short*)p; p += (size_t)B * TCe * 2;
  unsigned short* vb = (unsigned short*)p; p += (size_t)B * TCe * 2;
  unsigned short* aT = (unsigned short*)p; p += (size_t)B * TCe * 2;
  float* gmean = (float*)p; p += 512;
  float* grstd = (float*)p; p += 512;
  float* mrow  = (float*)p; p += (size_t)T * 4;
  float* rinv  = (float*)p; p += (size_t)T * 4;
  unsigned short* PT = (unsigned short*)p; p += (size_t)T * T * 2;  // 32MB
  float* S = (float*)p;
  size_t used = (size_t)((char*)S - (char*)d_ws);
  size_t avail = ws_size > used ? ws_size - used : 0;
  int qs = T;
  while (qs > 64 && (size_t)qs * T * 4 > avail) qs >>= 1;

  // 1) GroupNorm
  gn_stats_k<<<B * 32, 256, 0, stream>>>(x, gmean, grstd);
  gn_apply_t_k<<<dim3(T / 64, C / 64, B), 256, 0, stream>>>(x, gns, gnb, gmean, grstd, hT);

  // 2) QKV projections. q folded with scale C^-0.5 = 1/16 (exact in bf16).
  gemm64_k<true, EPI_WT><<<dim3(T / 64, C / 64, B), 256, 0, stream>>>(
      wq, 0, C, hT, TCe, C, qT, TCe, C, bq, nullptr, 0, 0.0625f, C);
  gemm64_k<true, EPI_WT><<<dim3(T / 64, C / 64, B), 256, 0, stream>>>(
      wk, 0, C, hT, TCe, C, kT, TCe, C, bk, nullptr, 0, 1.0f, C);
  gemm64_k<true, EPI_PB><<<dim3(T / 64, C / 64, B), 256, 0, stream>>>(
      wvp, 0, C, hT, TCe, C, vb, TCe, T, bv, nullptr, 0, 1.0f, C);

  // 3) attention per batch: S = qT·kT^T, row softmax stats, PT = softmax^T, O = v·P
  for (int b = 0; b < B; ++b) {
    for (int q0 = 0; q0 < T; q0 += qs) {
      gemm64_k<false, EPI_PF><<<dim3(T / 64, qs / 64), 256, 0, stream>>>(
          qT + ((size_t)b * T + q0) * C, 0, C,
          kT + (size_t)b * T * C, 0, C,
          S, 0, T, nullptr, nullptr, 0, 1.0f, C);
      row_stats_k<<<qs, 256, 0, stream>>>(S, mrow + q0, rinv + q0);
      make_pt_k<<<dim3(T / 64, qs / 64), 256, 0, stream>>>(S, mrow + q0, rinv + q0, PT, q0);
    }
    gemm64_k<false, EPI_WT><<<dim3(T / 64, C / 64), 256, 0, stream>>>(
        vb + (size_t)b * TCe, 0, T,
        PT, 0, T,
        aT + (size_t)b * TCe, 0, C, nullptr, nullptr, 0, 1.0f, T);
  }

  // 4) final projection + bias + residual
  gemm64_k<true, EPI_FIN><<<dim3(T / 64, C / 64, B), 256, 0, stream>>>(
      wo, 0, C, aT, TCe, C, out, TCe, T, bo, x, TCe, 1.0f, C);
}

// Round 2
// 216.496 us; speedup vs baseline: 2.1596x; 2.1596x over previous
//
#include <hip/hip_runtime.h>

typedef float f32x4 __attribute__((ext_vector_type(4)));
typedef short s16x8 __attribute__((ext_vector_type(8)));

__device__ __forceinline__ unsigned short f2bf(float f) {
  unsigned int u = __float_as_uint(f);
  u += 0x7fffu + ((u >> 16) & 1u);
  return (unsigned short)(u >> 16);
}

template <typename T>
__device__ __forceinline__ void gload16(const T* g, T* l) {
  __builtin_amdgcn_global_load_lds(
      (const __attribute__((address_space(1))) void*)g,
      (__attribute__((address_space(3))) void*)l, 16, 0, 0);
}

// ---------------- GroupNorm stats: one block per (b,g) ----------------
__global__ __launch_bounds__(256) void gn_stats_k(const float* __restrict__ x,
                                                  float* __restrict__ meanv,
                                                  float* __restrict__ rstdv) {
  const int bg = blockIdx.x;  // b*32+g ; group covers 8 contiguous channels
  const float4* base = (const float4*)(x + (size_t)bg * 8 * 4096);
  float s = 0.f, q = 0.f;
  for (int i = threadIdx.x; i < 8192; i += 256) {
    float4 v = base[i];
    s += v.x + v.y + v.z + v.w;
    q += v.x * v.x + v.y * v.y + v.z * v.z + v.w * v.w;
  }
  for (int o = 32; o; o >>= 1) { s += __shfl_down(s, o); q += __shfl_down(q, o); }
  __shared__ float ss[4], sq[4];
  const int wv = threadIdx.x >> 6;
  if ((threadIdx.x & 63) == 0) { ss[wv] = s; sq[wv] = q; }
  __syncthreads();
  if (threadIdx.x == 0) {
    s = ss[0] + ss[1] + ss[2] + ss[3];
    q = sq[0] + sq[1] + sq[2] + sq[3];
    float mu = s * (1.f / 32768.f);
    float var = q * (1.f / 32768.f) - mu * mu;
    meanv[bg] = mu;
    rstdv[bg] = rsqrtf(var + 1e-6f);
  }
}

// ------------- GroupNorm apply + transpose: write hT[b][t][c] bf16 -------------
__global__ __launch_bounds__(256) void gn_apply_t_k(const float* __restrict__ x,
    const float* __restrict__ gamma, const float* __restrict__ beta,
    const float* __restrict__ meanv, const float* __restrict__ rstdv,
    unsigned short* __restrict__ hT) {
  __shared__ unsigned short tile[64][72];
  const int b = blockIdx.z, c0 = blockIdx.y * 64, t0 = blockIdx.x * 64;
  const int tid = threadIdx.x;
  {
    const int tr = tid >> 4, tc = (tid & 15) * 4;
    const float* xb = x + ((size_t)b * 256 + c0) * 4096 + t0;
    for (int p2 = 0; p2 < 4; ++p2) {
      int cl = p2 * 16 + tr;
      int c = c0 + cl;
      int bg = b * 32 + (c >> 3);
      float ga = gamma[c] * rstdv[bg];
      float be = beta[c] - meanv[bg] * ga;
      float4 v = *(const float4*)(xb + (size_t)cl * 4096 + tc);
      tile[cl][tc + 0] = f2bf(v.x * ga + be);
      tile[cl][tc + 1] = f2bf(v.y * ga + be);
      tile[cl][tc + 2] = f2bf(v.z * ga + be);
      tile[cl][tc + 3] = f2bf(v.w * ga + be);
    }
  }
  __syncthreads();
  {
    const int orow = tid >> 3, oc = (tid & 7) * 8;
    unsigned short* hb = hT + ((size_t)b * 4096 + t0) * 256 + c0;
    for (int p2 = 0; p2 < 2; ++p2) {
      int tl = p2 * 32 + orow;
      s16x8 w;
#pragma unroll
      for (int j = 0; j < 8; ++j) w[j] = (short)tile[oc + j][tl];
      *(s16x8*)(hb + (size_t)tl * 256 + oc) = w;
    }
  }
}

// ---------------- generic 64x64-tile MFMA GEMM (projections) ----------------
// OUT[m][n] = sum_k A[m][k] * BT[n][k]   (both operands K-major)
enum { EPI_WT = 0, EPI_PB = 1, EPI_PF = 2, EPI_FIN = 3 };

template <bool AF32, int EPI>
__global__ __launch_bounds__(256) void gemm64_k(
    const void* __restrict__ Ap, long long sA, int lda,
    const unsigned short* __restrict__ Bp, long long sB, int ldb,
    void* __restrict__ Op, long long sO, int ldo,
    const float* __restrict__ bias,
    const float* __restrict__ xadd, long long sX,
    float scale, int K) {
  __shared__ s16x8 lsA[4][64];
  __shared__ s16x8 lsB[4][64];
  const int tid = threadIdx.x;
  const int m0 = blockIdx.y * 64, n0 = blockIdx.x * 64;
  const int z = blockIdx.z;
  const int lane = tid & 63, wv = tid >> 6;
  const int lrow = lane & 15, lg = lane >> 4;
  const int srow = tid >> 2, scg = tid & 3;
  const int swrow = srow ^ (scg << 1);  // bank swizzle

  f32x4 acc[4];
#pragma unroll
  for (int i = 0; i < 4; ++i) acc[i] = (f32x4){0.f, 0.f, 0.f, 0.f};

  const unsigned short* Bb = Bp + (size_t)z * sB + (size_t)(n0 + srow) * ldb + scg * 8;

  for (int k0 = 0; k0 < K; k0 += 32) {
    if (AF32) {
      const float* ap = (const float*)Ap + (size_t)z * sA + (size_t)(m0 + srow) * lda + k0 + scg * 8;
      float4 v0 = *(const float4*)ap;
      float4 v1 = *(const float4*)(ap + 4);
      s16x8 w;
      w[0] = (short)f2bf(v0.x); w[1] = (short)f2bf(v0.y);
      w[2] = (short)f2bf(v0.z); w[3] = (short)f2bf(v0.w);
      w[4] = (short)f2bf(v1.x); w[5] = (short)f2bf(v1.y);
      w[6] = (short)f2bf(v1.z); w[7] = (short)f2bf(v1.w);
      lsA[scg][swrow] = w;
    } else {
      const unsigned short* ap = (const unsigned short*)Ap + (size_t)z * sA + (size_t)(m0 + srow) * lda + k0 + scg * 8;
      lsA[scg][swrow] = *(const s16x8*)ap;
    }
    lsB[scg][swrow] = *(const s16x8*)(Bb + k0);
    __syncthreads();
    s16x8 af = lsA[lg][(wv * 16 + lrow) ^ (lg << 1)];
#pragma unroll
    for (int nt = 0; nt < 4; ++nt) {
      s16x8 bf = lsB[lg][(nt * 16 + lrow) ^ (lg << 1)];
      acc[nt] = __builtin_amdgcn_mfma_f32_16x16x32_bf16(af, bf, acc[nt], 0, 0, 0);
    }
    __syncthreads();
  }

  const int mb = m0 + wv * 16 + lg * 4;
  float bv0 = 0.f, bv1 = 0.f, bv2 = 0.f, bv3 = 0.f;
  if (EPI != EPI_PF) {
    if (bias) { bv0 = bias[mb]; bv1 = bias[mb + 1]; bv2 = bias[mb + 2]; bv3 = bias[mb + 3]; }
  }
#pragma unroll
  for (int nt = 0; nt < 4; ++nt) {
    const int n = n0 + nt * 16 + lrow;
    if (EPI == EPI_WT) {
      ushort4 pk;
      pk.x = f2bf((acc[nt][0] + bv0) * scale);
      pk.y = f2bf((acc[nt][1] + bv1) * scale);
      pk.z = f2bf((acc[nt][2] + bv2) * scale);
      pk.w = f2bf((acc[nt][3] + bv3) * scale);
      *(ushort4*)((unsigned short*)Op + (size_t)z * sO + (size_t)n * ldo + mb) = pk;
    } else if (EPI == EPI_PB) {
      unsigned short* o = (unsigned short*)Op + (size_t)z * sO;
      o[(size_t)(mb + 0) * ldo + n] = f2bf(acc[nt][0] + bv0);
      o[(size_t)(mb + 1) * ldo + n] = f2bf(acc[nt][1] + bv1);
      o[(size_t)(mb + 2) * ldo + n] = f2bf(acc[nt][2] + bv2);
      o[(size_t)(mb + 3) * ldo + n] = f2bf(acc[nt][3] + bv3);
    } else if (EPI == EPI_FIN) {
      float* o = (float*)Op + (size_t)z * sO;
      const float* xa = xadd + (size_t)z * sX;
      o[(size_t)(mb + 0) * ldo + n] = acc[nt][0] + bv0 + xa[(size_t)(mb + 0) * ldo + n];
      o[(size_t)(mb + 1) * ldo + n] = acc[nt][1] + bv1 + xa[(size_t)(mb + 1) * ldo + n];
      o[(size_t)(mb + 2) * ldo + n] = acc[nt][2] + bv2 + xa[(size_t)(mb + 2) * ldo + n];
      o[(size_t)(mb + 3) * ldo + n] = acc[nt][3] + bv3 + xa[(size_t)(mb + 3) * ldo + n];
    }
  }
}

// ---------------- pass 1: fused S + online softmax stats ----------------
// grid (T/128, KS1, B), 256 threads. Block: 128 q rows x 1024 k cols.
#define KS1 4
__global__ __launch_bounds__(256) void attn_stats_k(
    const unsigned short* __restrict__ qT,  // [B][T][C]
    const unsigned short* __restrict__ kT,  // [B][T][C]
    float* __restrict__ pm, float* __restrict__ pl) {  // [B][KS1][T]
  __shared__ unsigned short kbuf[2][64 * 256];
  const int tid = threadIdx.x;
  const int b = blockIdx.z;
  const int Q0 = blockIdx.x * 128;
  const int kc = blockIdx.y;  // k rows [kc*1024, +1024)
  const int lane = tid & 63, w = tid >> 6;
  const int lrow = lane & 15, lg = lane >> 4;

  const unsigned short* qb = qT + (size_t)b * (4096 * 256);
  const unsigned short* kb = kT + (size_t)b * (4096 * 256);

  // A-frags: qT rows, pinned in registers
  s16x8 af[2][8];
#pragma unroll
  for (int mt = 0; mt < 2; ++mt)
#pragma unroll
    for (int ks = 0; ks < 8; ++ks)
      af[mt][ks] = *(const s16x8*)(qb + (size_t)(Q0 + mt * 64 + w * 16 + lrow) * 256 + ks * 32 + lg * 8);

  float st_m[8], st_l[8];
#pragma unroll
  for (int s = 0; s < 8; ++s) { st_m[s] = 0.f; st_l[s] = 0.f; }

  int cur = 0;
  {  // prologue stage: kT tile 64 rows x 32 chunks, pre-swizzled source
    const unsigned short* src = kb + (size_t)(kc * 1024) * 256;
#pragma unroll
    for (int rep = 0; rep < 8; ++rep) {
      int i = rep * 256 + tid;
      int row = i >> 5, c8 = i & 31;
      int c8s = c8 ^ (row & 7);
      gload16(src + (size_t)row * 256 + c8s * 8, &kbuf[0][(i - lane) * 8]);
    }
  }
  __syncthreads();

  for (int it = 0; it < 16; ++it) {
    if (it + 1 < 16) {
      const unsigned short* src = kb + (size_t)(kc * 1024 + (it + 1) * 64) * 256;
#pragma unroll
      for (int rep = 0; rep < 8; ++rep) {
        int i = rep * 256 + tid;
        int row = i >> 5, c8 = i & 31;
        int c8s = c8 ^ (row & 7);
        gload16(src + (size_t)row * 256 + c8s * 8, &kbuf[cur ^ 1][(i - lane) * 8]);
      }
    }
    f32x4 acc[2][4];
#pragma unroll
    for (int mt = 0; mt < 2; ++mt)
#pragma unroll
      for (int nt = 0; nt < 4; ++nt) acc[mt][nt] = (f32x4){0.f, 0.f, 0.f, 0.f};
#pragma unroll
    for (int ks = 0; ks < 8; ++ks) {
#pragma unroll
      for (int nt = 0; nt < 4; ++nt) {
        int row = nt * 16 + lrow;
        int ch = (ks * 4 + lg) ^ (row & 7);
        s16x8 bf = *(const s16x8*)&kbuf[cur][row * 256 + ch * 8];
        acc[0][nt] = __builtin_amdgcn_mfma_f32_16x16x32_bf16(af[0][ks], bf, acc[0][nt], 0, 0, 0);
        acc[1][nt] = __builtin_amdgcn_mfma_f32_16x16x32_bf16(af[1][ks], bf, acc[1][nt], 0, 0, 0);
      }
    }
    // online (m,l) update, branchless
#pragma unroll
    for (int mt = 0; mt < 2; ++mt)
#pragma unroll
      for (int j = 0; j < 4; ++j) {
        int s = mt * 4 + j;
        float v0 = acc[mt][0][j], v1 = acc[mt][1][j], v2 = acc[mt][2][j], v3 = acc[mt][3][j];
        float mx = fmaxf(fmaxf(v0, v1), fmaxf(v2, v3));
        float mn = fmaxf(st_m[s], mx);
        st_l[s] = st_l[s] * __expf(st_m[s] - mn) +
                  __expf(v0 - mn) + __expf(v1 - mn) + __expf(v2 - mn) + __expf(v3 - mn);
        st_m[s] = mn;
      }
    __syncthreads();
    cur ^= 1;
  }
  // merge across the 16 lrow lanes (same q rows, different k slices)
#pragma unroll
  for (int s = 0; s < 8; ++s) {
    float m = st_m[s], l = st_l[s];
#pragma unroll
    for (int o = 1; o < 16; o <<= 1) {
      float mo = __shfl_xor(m, o);
      float lo = __shfl_xor(l, o);
      float mn = fmaxf(m, mo);
      l = l * __expf(m - mn) + lo * __expf(mo - mn);
      m = mn;
    }
    st_m[s] = m; st_l[s] = l;
  }
  if (lrow == 0) {
    float* pmb = pm + ((size_t)b * KS1 + kc) * 4096;
    float* plb = pl + ((size_t)b * KS1 + kc) * 4096;
#pragma unroll
    for (int mt = 0; mt < 2; ++mt)
#pragma unroll
      for (int j = 0; j < 4; ++j) {
        int q = Q0 + mt * 64 + w * 16 + lg * 4 + j;
        pmb[q] = st_m[mt * 4 + j];
        plb[q] = st_l[mt * 4 + j];
      }
  }
}

__global__ __launch_bounds__(256) void stats_merge_k(const float* __restrict__ pm,
    const float* __restrict__ pl, float* __restrict__ ma, float* __restrict__ ra) {
  int i = blockIdx.x * 256 + threadIdx.x;  // over B*T
  int b = i >> 12, q = i & 4095;
  const float* pmb = pm + (size_t)b * KS1 * 4096 + q;
  const float* plb = pl + (size_t)b * KS1 * 4096 + q;
  float m = -1e30f;
#pragma unroll
  for (int c = 0; c < KS1; ++c) m = fmaxf(m, pmb[(size_t)c * 4096]);
  float l = 0.f;
#pragma unroll
  for (int c = 0; c < KS1; ++c) l += plb[(size_t)c * 4096] * __expf(pmb[(size_t)c * 4096] - m);
  ma[i] = m;
  ra[i] = 1.f / l;
}

// ---------------- pass 2: fused S recompute + softmax + PV ----------------
// grid (T/64, B), 512 threads (8 waves). Block owns output k-tile [K0,K0+64).
__global__ __launch_bounds__(512) void attn_pv_k(
    const unsigned short* __restrict__ qT,
    const unsigned short* __restrict__ kT,
    const unsigned short* __restrict__ vb,   // [B][C][T]
    const float* __restrict__ ma, const float* __restrict__ ra,  // [B][T]
    unsigned short* __restrict__ aT) {       // [B][T][C]
  __shared__ unsigned short qbuf[2][64 * 256];  // 32KB x2
  __shared__ unsigned short vbuf[2][256 * 64];  // 32KB x2
  __shared__ unsigned short P[64 * 72];         // 9KB, padded stride
  const int tid = threadIdx.x;
  const int b = blockIdx.y;
  const int K0 = blockIdx.x * 64;
  const int lane = tid & 63, w = tid >> 6;
  const int lrow = lane & 15, lg = lane >> 4;
  const int kr = w >> 2, qh = w & 3;  // phase-1 roles: 32 k-rows x 16 q-cols
  const int cb = w * 32;              // phase-2 role: 32 c-rows x 64 k

  const unsigned short* qg = qT + (size_t)b * (4096 * 256);
  const unsigned short* kg = kT + (size_t)b * (4096 * 256);
  const unsigned short* vg = vb + (size_t)b * (4096 * 256);
  const float* mg = ma + (size_t)b * 4096;
  const float* rg = ra + (size_t)b * 4096;

  // kT frags for this block's k rows (phase-1 A operand), pinned
  s16x8 kf[2][8];
#pragma unroll
  for (int mt = 0; mt < 2; ++mt)
#pragma unroll
    for (int ks = 0; ks < 8; ++ks)
      kf[mt][ks] = *(const s16x8*)(kg + (size_t)(K0 + kr * 32 + mt * 16 + lrow) * 256 + ks * 32 + lg * 8);

  f32x4 oacc[2][4];
#pragma unroll
  for (int mt = 0; mt < 2; ++mt)
#pragma unroll
    for (int nt = 0; nt < 4; ++nt) oacc[mt][nt] = (f32x4){0.f, 0.f, 0.f, 0.f};

  int cur = 0;
  {  // prologue: stage q-tile 0 (qT 64x512B rows; v 256x128B rows), swizzled source
#pragma unroll
    for (int rep = 0; rep < 4; ++rep) {
      int i = rep * 512 + tid;
      int row = i >> 5, c8 = i & 31, c8s = c8 ^ (row & 7);
      gload16(qg + (size_t)row * 256 + c8s * 8, &qbuf[0][(i - lane) * 8]);
    }
#pragma unroll
    for (int rep = 0; rep < 4; ++rep) {
      int i = rep * 512 + tid;
      int row = i >> 3, c8 = i & 7, c8s = c8 ^ (row & 7);
      gload16(vg + (size_t)row * 4096 + c8s * 8, &vbuf[0][(i - lane) * 8]);
    }
  }
  __syncthreads();

  for (int qi = 0; qi < 64; ++qi) {
    const int q0 = qi * 64;
    if (qi + 1 < 64) {
      const unsigned short* qs = qg + (size_t)(q0 + 64) * 256;
#pragma unroll
      for (int rep = 0; rep < 4; ++rep) {
        int i = rep * 512 + tid;
        int row = i >> 5, c8 = i & 31, c8s = c8 ^ (row & 7);
        gload16(qs + (size_t)row * 256 + c8s * 8, &qbuf[cur ^ 1][(i - lane) * 8]);
      }
#pragma unroll
      for (int rep = 0; rep < 4; ++rep) {
        int i = rep * 512 + tid;
        int row = i >> 3, c8 = i & 7, c8s = c8 ^ (row & 7);
        gload16(vg + (size_t)row * 4096 + (q0 + 64) + c8s * 8, &vbuf[cur ^ 1][(i - lane) * 8]);
      }
    }
    // phase 1: S^T tile (rows = k, cols = q) -> P in LDS
    f32x4 sacc0 = (f32x4){0.f, 0.f, 0.f, 0.f};
    f32x4 sacc1 = (f32x4){0.f, 0.f, 0.f, 0.f};
    {
      const int qrow = qh * 16 + lrow;
#pragma unroll
      for (int ks = 0; ks < 8; ++ks) {
        int ch = (ks * 4 + lg) ^ (qrow & 7);
        s16x8 bf = *(const s16x8*)&qbuf[cur][qrow * 256 + ch * 8];
        sacc0 = __builtin_amdgcn_mfma_f32_16x16x32_bf16(kf[0][ks], bf, sacc0, 0, 0, 0);
        sacc1 = __builtin_amdgcn_mfma_f32_16x16x32_bf16(kf[1][ks], bf, sacc1, 0, 0, 0);
      }
    }
    {
      const int qgl = q0 + qh * 16 + lrow;
      const float m2 = mg[qgl], rr = rg[qgl];
#pragma unroll
      for (int j = 0; j < 4; ++j) {
        P[(kr * 32 + 0 * 16 + lg * 4 + j) * 72 + qh * 16 + lrow] = f2bf(__expf(sacc0[j] - m2) * rr);
        P[(kr * 32 + 1 * 16 + lg * 4 + j) * 72 + qh * 16 + lrow] = f2bf(__expf(sacc1[j] - m2) * rr);
      }
    }
    __syncthreads();  // P visible; staged tiles also complete (vmcnt drain)
    // phase 2: oacc[c][k] += v'[c][q-tile] * P^T[k][q-tile]
#pragma unroll
    for (int ks = 0; ks < 2; ++ks) {
      s16x8 avf[2];
#pragma unroll
      for (int mt = 0; mt < 2; ++mt) {
        int crow = cb + mt * 16 + lrow;
        int ch = (ks * 4 + lg) ^ (crow & 7);
        avf[mt] = *(const s16x8*)&vbuf[cur][crow * 64 + ch * 8];
      }
#pragma unroll
      for (int nt = 0; nt < 4; ++nt) {
        s16x8 pf = *(const s16x8*)&P[(nt * 16 + lrow) * 72 + ks * 32 + lg * 8];
        oacc[0][nt] = __builtin_amdgcn_mfma_f32_16x16x32_bf16(avf[0], pf, oacc[0][nt], 0, 0, 0);
        oacc[1][nt] = __builtin_amdgcn_mfma_f32_16x16x32_bf16(avf[1], pf, oacc[1][nt], 0, 0, 0);
      }
    }
    __syncthreads();  // P + tiles consumed; next iter may overwrite
    cur ^= 1;
  }
  // epilogue: aT[K0+k][c] = oacc
  unsigned short* ab = aT + (size_t)b * (4096 * 256);
#pragma unroll
  for (int mt = 0; mt < 2; ++mt)
#pragma unroll
    for (int nt = 0; nt < 4; ++nt) {
      int k = K0 + nt * 16 + lrow;
      int c = cb + mt * 16 + lg * 4;
      ushort4 pk;
      pk.x = f2bf(oacc[mt][nt][0]);
      pk.y = f2bf(oacc[mt][nt][1]);
      pk.z = f2bf(oacc[mt][nt][2]);
      pk.w = f2bf(oacc[mt][nt][3]);
      *(ushort4*)(ab + (size_t)k * 256 + c) = pk;
    }
}

extern "C" void kernel_launch(void* const* d_in, const int* in_sizes, int n_in,
                              void* d_out, int out_size, void* d_ws, size_t ws_size,
                              hipStream_t stream) {
  const float* x   = (const float*)d_in[0];
  const float* gns = (const float*)d_in[1];
  const float* gnb = (const float*)d_in[2];
  const float* wq  = (const float*)d_in[3];
  const float* bq  = (const float*)d_in[4];
  const float* wk  = (const float*)d_in[5];
  const float* bk  = (const float*)d_in[6];
  const float* wvp = (const float*)d_in[7];
  const float* bv  = (const float*)d_in[8];
  const float* wo  = (const float*)d_in[9];
  const float* bo  = (const float*)d_in[10];
  float* out = (float*)d_out;

  const int B = 4, C = 256, T = 4096;
  const long long TCe = (long long)T * C;  // 1M elems

  char* p = (char*)d_ws;
  unsigned short* hT = (unsigned short*)p; p += (size_t)B * TCe * 2;
  unsigned short* qT = (unsigned short*)p; p += (size_t)B * TCe * 2;
  unsigned short* kT = (unsigned short*)p; p += (size_t)B * TCe * 2;
  unsigned short* vb = (unsigned short*)p; p += (size_t)B * TCe * 2;
  unsigned short* aT = (unsigned short*)p; p += (size_t)B * TCe * 2;
  float* gmean = (float*)p; p += 512;
  float* grstd = (float*)p; p += 512;
  float* pm = (float*)p; p += (size_t)B * KS1 * T * 4;
  float* pl = (float*)p; p += (size_t)B * KS1 * T * 4;
  float* ma = (float*)p; p += (size_t)B * T * 4;
  float* ra = (float*)p; p += (size_t)B * T * 4;

  // 1) GroupNorm
  gn_stats_k<<<B * 32, 256, 0, stream>>>(x, gmean, grstd);
  gn_apply_t_k<<<dim3(T / 64, C / 64, B), 256, 0, stream>>>(x, gns, gnb, gmean, grstd, hT);

  // 2) QKV projections. q folded with scale C^-0.5 = 1/16 (exact in bf16).
  gemm64_k<true, EPI_WT><<<dim3(T / 64, C / 64, B), 256, 0, stream>>>(
      wq, 0, C, hT, TCe, C, qT, TCe, C, bq, nullptr, 0, 0.0625f, C);
  gemm64_k<true, EPI_WT><<<dim3(T / 64, C / 64, B), 256, 0, stream>>>(
      wk, 0, C, hT, TCe, C, kT, TCe, C, bk, nullptr, 0, 1.0f, C);
  gemm64_k<true, EPI_PB><<<dim3(T / 64, C / 64, B), 256, 0, stream>>>(
      wvp, 0, C, hT, TCe, C, vb, TCe, T, bv, nullptr, 0, 1.0f, C);

  // 3) fused attention: pass 1 stats, merge, pass 2 PV
  attn_stats_k<<<dim3(T / 128, KS1, B), 256, 0, stream>>>(qT, kT, pm, pl);
  stats_merge_k<<<B * T / 256, 256, 0, stream>>>(pm, pl, ma, ra);
  attn_pv_k<<<dim3(T / 64, B), 512, 0, stream>>>(qT, kT, vb, ma, ra, aT);

  // 4) final projection + bias + residual
  gemm64_k<true, EPI_FIN><<<dim3(T / 64, C / 64, B), 256, 0, stream>>>(
      wo, 0, C, aT, TCe, C, out, TCe, T, bo, x, TCe, 1.0f, C);
}